// Round 3
// baseline (537.223 us; speedup 1.0000x reference)
//
#include <hip/hip_runtime.h>

using u16 = unsigned short;
using u32 = unsigned int;

typedef __attribute__((ext_vector_type(8))) _Float16 f16x8;
typedef __attribute__((ext_vector_type(4))) float floatx4;

#define NTOK 512
#define DIM  256   // NODE_DIM == HIDDEN
#define EDIM 128

// ---------------------------------------------------------------------------
// Kernel 1: blocks 0..127: LayerNorm + proj (q,k) + qd/kd pre-GEMMs (4 rows
// per block).  Blocks 128..143: convert w_p = o_w[:,0:256] to f16.
// Outputs: q,k f16 [512][256]; wp f16 [128][256];
//          qdb = q@w_d^T + o_b (f32), kd = k@w_d^T (f32)
// ---------------------------------------------------------------------------
__global__ __launch_bounds__(256) void k1_ln_proj(
    const float* __restrict__ node, const float* __restrict__ ln_w,
    const float* __restrict__ ln_b, const float* __restrict__ proj_w,
    const float* __restrict__ proj_b, const float* __restrict__ o_w,
    const float* __restrict__ o_b,
    u16* __restrict__ qo, u16* __restrict__ ko, u16* __restrict__ wpf,
    float* __restrict__ qdb, float* __restrict__ kdo)
{
    const int tid = threadIdx.x;

    if (blockIdx.x >= 128) {
        // w_p f32 -> f16 conversion: 16 blocks x 256 thr x 8 elems = 128*256
        const int g   = (blockIdx.x - 128) * 256 + tid;
        const int idx = g * 8;
        const int e   = idx >> 8;
        const int h   = idx & 255;
        const float4 lo = *(const float4*)(o_w + e*(2*DIM) + h);
        const float4 hi = *(const float4*)(o_w + e*(2*DIM) + h + 4);
        f16x8 v;
        v[0] = (_Float16)lo.x; v[1] = (_Float16)lo.y;
        v[2] = (_Float16)lo.z; v[3] = (_Float16)lo.w;
        v[4] = (_Float16)hi.x; v[5] = (_Float16)hi.y;
        v[6] = (_Float16)hi.z; v[7] = (_Float16)hi.w;
        *(f16x8*)(wpf + idx) = v;
        return;
    }

    __shared__ float sn[4][DIM];       // normalized rows
    __shared__ float sfull[4][2*DIM];  // s = LN@proj_w^T + proj_b (q|k concat)
    const int wid  = tid >> 6;
    const int lane = tid & 63;
    const int n0   = blockIdx.x * 4;

    // --- LayerNorm: wave w -> row n0+w ---
    {
        const int n = n0 + wid;
        const int d = lane * 4;
        const float4 x = *(const float4*)(node + n*DIM + d);
        float s  = x.x + x.y + x.z + x.w;
        float ss = x.x*x.x + x.y*x.y + x.z*x.z + x.w*x.w;
        #pragma unroll
        for (int off = 32; off > 0; off >>= 1) {
            s  += __shfl_xor(s,  off);
            ss += __shfl_xor(ss, off);
        }
        const float mu   = s * (1.0f/DIM);
        const float var  = ss * (1.0f/DIM) - mu*mu;
        const float rstd = rsqrtf(var + 1e-5f);
        const float4 w = *(const float4*)(ln_w + d);
        const float4 b = *(const float4*)(ln_b + d);
        sn[wid][d+0] = (x.x-mu)*rstd*w.x + b.x;
        sn[wid][d+1] = (x.y-mu)*rstd*w.y + b.y;
        sn[wid][d+2] = (x.z-mu)*rstd*w.z + b.z;
        sn[wid][d+3] = (x.w-mu)*rstd*w.w + b.w;
    }
    __syncthreads();

    // --- proj: thread t computes cols c0=t (q) and c1=t+256 (k), 4 rows ---
    {
        const int c0 = tid, c1 = tid + DIM;
        const float bq = proj_b[c0], bk = proj_b[c1];
        float accq[4], acck[4];
        #pragma unroll
        for (int r = 0; r < 4; ++r) { accq[r] = bq; acck[r] = bk; }
        const float* w0p = proj_w + c0*DIM;
        const float* w1p = proj_w + c1*DIM;
        for (int d = 0; d < DIM; d += 4) {
            const float4 wa = *(const float4*)(w0p + d);
            const float4 wb = *(const float4*)(w1p + d);
            #pragma unroll
            for (int r = 0; r < 4; ++r) {
                const float s0 = sn[r][d+0], s1 = sn[r][d+1];
                const float s2 = sn[r][d+2], s3 = sn[r][d+3];
                accq[r] += wa.x*s0 + wa.y*s1 + wa.z*s2 + wa.w*s3;
                acck[r] += wb.x*s0 + wb.y*s1 + wb.z*s2 + wb.w*s3;
            }
        }
        #pragma unroll
        for (int r = 0; r < 4; ++r) {
            sfull[r][c0] = accq[r];
            sfull[r][c1] = acck[r];
            qo[(n0+r)*DIM + c0] = __builtin_bit_cast(u16, (_Float16)accq[r]);
            ko[(n0+r)*DIM + c0] = __builtin_bit_cast(u16, (_Float16)acck[r]);
        }
    }
    __syncthreads();

    // --- qd[n,e] = q[n,:]·w_d[e,:] + o_b[e] ;  kd[n,e] = k[n,:]·w_d[e,:] ---
    {
        const int e    = tid & (EDIM-1);
        const int half = tid >> 7;             // 0: qd (q part), 1: kd (k part)
        const float* wd = o_w + e*(2*DIM) + DIM;  // w_d = o_w[:, 256:512]
        float a[4] = {0.f, 0.f, 0.f, 0.f};
        for (int h = 0; h < DIM; h += 4) {
            const float4 w = *(const float4*)(wd + h);
            #pragma unroll
            for (int r = 0; r < 4; ++r) {
                const float* sp = &sfull[r][half*DIM + h];
                a[r] += w.x*sp[0] + w.y*sp[1] + w.z*sp[2] + w.w*sp[3];
            }
        }
        if (half == 0) {
            const float ob = o_b[e];
            #pragma unroll
            for (int r = 0; r < 4; ++r) qdb[(n0+r)*EDIM + e] = a[r] + ob;
        } else {
            #pragma unroll
            for (int r = 0; r < 4; ++r) kdo[(n0+r)*EDIM + e] = a[r];
        }
    }
}

// ---------------------------------------------------------------------------
// Kernel 2: x[i,j,e] = (q[j,:]*k[i,:])·w_p[e,:] + qd[j,e] - kd[i,e]
// Grid: 1024 blocks = 2 e-tiles(64) x 8 j-tiles(64) x 64 i-groups(8).
// Block: 256 thr = 4 waves, all sharing one 64j x 64e tile; waves split the
// 8 i's (2 each).  q-tile + wp-tile live in 64 KB XOR-swizzled LDS (b128
// reads spread uniformly over banks; 16B alignment kept).  Per-wave regs
// ~190 (acc 64 + qiv 64 + transients) -> 2 blocks/CU, 2 waves/SIMD.
// No barrier inside the i-loop; store-BW-bound by design.
// ---------------------------------------------------------------------------
__global__ __launch_bounds__(256, 2) void k2_edge(
    const u16* __restrict__ qg, const u16* __restrict__ kg,
    const float* __restrict__ qdb, const float* __restrict__ kdg,
    const u16* __restrict__ wpg, float* __restrict__ outp)
{
    __shared__ uint4 sq4[2048];   // q  tile: 64 rows x 32 swizzled 16B chunks
    __shared__ uint4 sp4[2048];   // wp tile: same layout

    const int tid  = threadIdx.x;
    const int wid  = tid >> 6;
    const int lane = tid & 63;
    const int col  = lane & 15;
    const int quad = lane >> 4;
    const int bid  = blockIdx.x;
    const int e0 = (bid & 1) * 64;
    const int j0 = ((bid >> 1) & 7) * 64;
    const int i0 = (bid >> 4) * 8;

    // --- stage q[j0:j0+64][0:256] and wp[e0:e0+64][0:256] (f16) into LDS ---
    {
        const int row   = tid >> 2;        // 0..63
        const int cbase = (tid & 3) * 8;   // chunk base (chunk = 8 f16 = 16B)
        const int sw    = row & 7;
        #pragma unroll
        for (int u = 0; u < 8; ++u) {
            const int c = cbase + u;
            sq4[row*32 + (c ^ sw)] = *(const uint4*)(qg  + (j0 + row)*DIM + c*8);
            sp4[row*32 + (c ^ sw)] = *(const uint4*)(wpg + (e0 + row)*DIM + c*8);
        }
    }
    __syncthreads();

    const u16* sq = (const u16*)sq4;
    const u16* sp = (const u16*)sp4;
    const int csw = col & 7;   // row&7 for row = *t*16+col

    // qd (+o_b) in C-layout — i-independent part of the accumulator init
    floatx4 qiv[4][4];
    #pragma unroll
    for (int mt = 0; mt < 4; ++mt) {
        #pragma unroll
        for (int et = 0; et < 4; ++et) {
            const int ec = e0 + et*16 + col;
            #pragma unroll
            for (int r = 0; r < 4; ++r)
                qiv[mt][et][r] = qdb[(j0 + mt*16 + quad*4 + r) * EDIM + ec];
        }
    }

    #pragma unroll 1
    for (int t = 0; t < 2; ++t) {
        const int i = i0 + wid + t*4;      // each wave: 2 of the block's 8 i's

        float kdv[4];
        #pragma unroll
        for (int et = 0; et < 4; ++et)
            kdv[et] = kdg[i*EDIM + e0 + et*16 + col];

        floatx4 acc[4][4];
        #pragma unroll
        for (int mt = 0; mt < 4; ++mt)
            #pragma unroll
            for (int et = 0; et < 4; ++et)
                acc[mt][et] = qiv[mt][et] - kdv[et];

        const u16* kp = kg + i*DIM + quad*8;
        #pragma unroll
        for (int ks = 0; ks < 8; ++ks) {
            const f16x8 kv = __builtin_bit_cast(f16x8, *(const uint4*)(kp + ks*32));
            const int cs = ((ks*4 + quad) ^ csw) * 8;
            f16x8 bf[4], sa[4];
            #pragma unroll
            for (int et = 0; et < 4; ++et)
                bf[et] = *(const f16x8*)(sp + (et*16 + col)*DIM + cs);
            #pragma unroll
            for (int mt = 0; mt < 4; ++mt) {
                const f16x8 af = *(const f16x8*)(sq + (mt*16 + col)*DIM + cs);
                sa[mt] = af * kv;          // v_pk_mul_f16 x4
            }
            #pragma unroll
            for (int mt = 0; mt < 4; ++mt)
                #pragma unroll
                for (int et = 0; et < 4; ++et)
                    acc[mt][et] = __builtin_amdgcn_mfma_f32_16x16x32_f16(
                        sa[mt], bf[et], acc[mt][et], 0, 0, 0);
        }

        float* ob = outp + (size_t)i * (NTOK * EDIM);
        #pragma unroll
        for (int mt = 0; mt < 4; ++mt) {
            #pragma unroll
            for (int et = 0; et < 4; ++et) {
                const int ec = e0 + et*16 + col;
                #pragma unroll
                for (int r = 0; r < 4; ++r)
                    ob[(j0 + mt*16 + quad*4 + r) * EDIM + ec] = acc[mt][et][r];
            }
        }
    }
}

extern "C" void kernel_launch(void* const* d_in, const int* in_sizes, int n_in,
                              void* d_out, int out_size, void* d_ws, size_t ws_size,
                              hipStream_t stream) {
    const float* node   = (const float*)d_in[0];
    const float* ln_w   = (const float*)d_in[1];
    const float* ln_b   = (const float*)d_in[2];
    const float* proj_w = (const float*)d_in[3];
    const float* proj_b = (const float*)d_in[4];
    const float* o_w    = (const float*)d_in[5];
    const float* o_b    = (const float*)d_in[6];
    float* outp = (float*)d_out;

    // ws: q f16[512][256] | k f16[512][256] | wp f16[128][256] | qdb f32[512][128] | kd f32[512][128]
    u16*   qws = (u16*)d_ws;
    u16*   kws = qws + NTOK*DIM;
    u16*   wpf = kws + NTOK*DIM;
    float* qdb = (float*)(wpf + EDIM*DIM);
    float* kdw = qdb + NTOK*EDIM;

    hipLaunchKernelGGL(k1_ln_proj, dim3(144), dim3(256), 0, stream,
                       node, ln_w, ln_b, proj_w, proj_b, o_w, o_b,
                       qws, kws, wpf, qdb, kdw);
    hipLaunchKernelGGL(k2_edge, dim3(1024), dim3(256), 0, stream,
                       qws, kws, qdb, kdw, wpf, outp);
}

// Round 4
// 315.683 us; speedup vs baseline: 1.7018x; 1.7018x over previous
//
#include <hip/hip_runtime.h>

using u16 = unsigned short;
using u32 = unsigned int;

typedef __attribute__((ext_vector_type(8))) _Float16 f16x8;
typedef __attribute__((ext_vector_type(4))) float floatx4;

#define NTOK 512
#define DIM  256   // NODE_DIM == HIDDEN
#define EDIM 128

// ---------------------------------------------------------------------------
// Kernel 1: blocks 0..127: LayerNorm + proj (q,k) + qd/kd pre-GEMMs (4 rows
// per block).  Blocks 128..143: convert w_p = o_w[:,0:256] to f16.
// Outputs: q,k f16 [512][256]; wp f16 [128][256];
//          qdb = q@w_d^T + o_b (f32), kd = k@w_d^T (f32)
// ---------------------------------------------------------------------------
__global__ __launch_bounds__(256) void k1_ln_proj(
    const float* __restrict__ node, const float* __restrict__ ln_w,
    const float* __restrict__ ln_b, const float* __restrict__ proj_w,
    const float* __restrict__ proj_b, const float* __restrict__ o_w,
    const float* __restrict__ o_b,
    u16* __restrict__ qo, u16* __restrict__ ko, u16* __restrict__ wpf,
    float* __restrict__ qdb, float* __restrict__ kdo)
{
    const int tid = threadIdx.x;

    if (blockIdx.x >= 128) {
        // w_p f32 -> f16 conversion: 16 blocks x 256 thr x 8 elems = 128*256
        const int g   = (blockIdx.x - 128) * 256 + tid;
        const int idx = g * 8;
        const int e   = idx >> 8;
        const int h   = idx & 255;
        const float4 lo = *(const float4*)(o_w + e*(2*DIM) + h);
        const float4 hi = *(const float4*)(o_w + e*(2*DIM) + h + 4);
        f16x8 v;
        v[0] = (_Float16)lo.x; v[1] = (_Float16)lo.y;
        v[2] = (_Float16)lo.z; v[3] = (_Float16)lo.w;
        v[4] = (_Float16)hi.x; v[5] = (_Float16)hi.y;
        v[6] = (_Float16)hi.z; v[7] = (_Float16)hi.w;
        *(f16x8*)(wpf + idx) = v;
        return;
    }

    __shared__ float sn[4][DIM];       // normalized rows
    __shared__ float sfull[4][2*DIM];  // s = LN@proj_w^T + proj_b (q|k concat)
    const int wid  = tid >> 6;
    const int lane = tid & 63;
    const int n0   = blockIdx.x * 4;

    // --- LayerNorm: wave w -> row n0+w ---
    {
        const int n = n0 + wid;
        const int d = lane * 4;
        const float4 x = *(const float4*)(node + n*DIM + d);
        float s  = x.x + x.y + x.z + x.w;
        float ss = x.x*x.x + x.y*x.y + x.z*x.z + x.w*x.w;
        #pragma unroll
        for (int off = 32; off > 0; off >>= 1) {
            s  += __shfl_xor(s,  off);
            ss += __shfl_xor(ss, off);
        }
        const float mu   = s * (1.0f/DIM);
        const float var  = ss * (1.0f/DIM) - mu*mu;
        const float rstd = rsqrtf(var + 1e-5f);
        const float4 w = *(const float4*)(ln_w + d);
        const float4 b = *(const float4*)(ln_b + d);
        sn[wid][d+0] = (x.x-mu)*rstd*w.x + b.x;
        sn[wid][d+1] = (x.y-mu)*rstd*w.y + b.y;
        sn[wid][d+2] = (x.z-mu)*rstd*w.z + b.z;
        sn[wid][d+3] = (x.w-mu)*rstd*w.w + b.w;
    }
    __syncthreads();

    // --- proj: thread t computes cols c0=t (q) and c1=t+256 (k), 4 rows ---
    {
        const int c0 = tid, c1 = tid + DIM;
        const float bq = proj_b[c0], bk = proj_b[c1];
        float accq[4], acck[4];
        #pragma unroll
        for (int r = 0; r < 4; ++r) { accq[r] = bq; acck[r] = bk; }
        const float* w0p = proj_w + c0*DIM;
        const float* w1p = proj_w + c1*DIM;
        for (int d = 0; d < DIM; d += 4) {
            const float4 wa = *(const float4*)(w0p + d);
            const float4 wb = *(const float4*)(w1p + d);
            #pragma unroll
            for (int r = 0; r < 4; ++r) {
                const float s0 = sn[r][d+0], s1 = sn[r][d+1];
                const float s2 = sn[r][d+2], s3 = sn[r][d+3];
                accq[r] += wa.x*s0 + wa.y*s1 + wa.z*s2 + wa.w*s3;
                acck[r] += wb.x*s0 + wb.y*s1 + wb.z*s2 + wb.w*s3;
            }
        }
        #pragma unroll
        for (int r = 0; r < 4; ++r) {
            sfull[r][c0] = accq[r];
            sfull[r][c1] = acck[r];
            qo[(n0+r)*DIM + c0] = __builtin_bit_cast(u16, (_Float16)accq[r]);
            ko[(n0+r)*DIM + c0] = __builtin_bit_cast(u16, (_Float16)acck[r]);
        }
    }
    __syncthreads();

    // --- qd[n,e] = q[n,:]·w_d[e,:] + o_b[e] ;  kd[n,e] = k[n,:]·w_d[e,:] ---
    {
        const int e    = tid & (EDIM-1);
        const int half = tid >> 7;             // 0: qd (q part), 1: kd (k part)
        const float* wd = o_w + e*(2*DIM) + DIM;  // w_d = o_w[:, 256:512]
        float a[4] = {0.f, 0.f, 0.f, 0.f};
        for (int h = 0; h < DIM; h += 4) {
            const float4 w = *(const float4*)(wd + h);
            #pragma unroll
            for (int r = 0; r < 4; ++r) {
                const float* sp = &sfull[r][half*DIM + h];
                a[r] += w.x*sp[0] + w.y*sp[1] + w.z*sp[2] + w.w*sp[3];
            }
        }
        if (half == 0) {
            const float ob = o_b[e];
            #pragma unroll
            for (int r = 0; r < 4; ++r) qdb[(n0+r)*EDIM + e] = a[r] + ob;
        } else {
            #pragma unroll
            for (int r = 0; r < 4; ++r) kdo[(n0+r)*EDIM + e] = a[r];
        }
    }
}

// ---------------------------------------------------------------------------
// Kernel 2: x[i,j,e] = (q[j,:]*k[i,:])·w_p[e,:] + qd[j,e] - kd[i,e]
// Grid: 1024 blocks = 2 e-tiles(64) x 8 j-tiles(64) x 64 i-groups(8).
// Block: 256 thr = 4 waves sharing one 64j x 64e tile; waves take 2 i's each.
// LDS (80 KB): q tile 32K + wp tile 32K (XOR-swizzled b128) + qd tile 16K
// (chunk-swizzled f32, folded in at store time -> NO qiv registers).
// Register demand ~115 < 128 cap -> __launch_bounds__(256,2), 2 blocks/CU,
// no scratch spill (round-3 failure mode).  Store-BW-bound by design.
// ---------------------------------------------------------------------------
__global__ __launch_bounds__(256, 2) void k2_edge(
    const u16* __restrict__ qg, const u16* __restrict__ kg,
    const float* __restrict__ qdb, const float* __restrict__ kdg,
    const u16* __restrict__ wpg, float* __restrict__ outp)
{
    __shared__ uint4 sq4[2048];   // q  tile: 64 rows x 32 swizzled 16B chunks
    __shared__ uint4 sp4[2048];   // wp tile: same layout
    __shared__ float sqd[4096];   // qd tile: 64j x 16 swizzled float4 chunks

    const int tid  = threadIdx.x;
    const int wid  = tid >> 6;
    const int lane = tid & 63;
    const int col  = lane & 15;
    const int quad = lane >> 4;
    const int bid  = blockIdx.x;
    const int e0 = (bid & 1) * 64;
    const int j0 = ((bid >> 1) & 7) * 64;
    const int i0 = (bid >> 4) * 8;

    // --- stage q[j0:+64][0:256], wp[e0:+64][0:256] (f16), qd[j0:+64][e0:+64] ---
    {
        const int row   = tid >> 2;        // 0..63
        const int cbase = (tid & 3) * 8;   // chunk base (chunk = 8 f16 = 16B)
        const int sw    = row & 7;
        #pragma unroll
        for (int u = 0; u < 8; ++u) {
            const int c = cbase + u;
            sq4[row*32 + (c ^ sw)] = *(const uint4*)(qg  + (j0 + row)*DIM + c*8);
            sp4[row*32 + (c ^ sw)] = *(const uint4*)(wpg + (e0 + row)*DIM + c*8);
        }
        // qd: lane=row, wave w stages float4-chunks 4w..4w+3, chunk-XOR swizzle
        const int qrow = tid & 63;
        const int cb   = (tid >> 6) * 4;
        #pragma unroll
        for (int u = 0; u < 4; ++u) {
            const int c = cb + u;          // float4 chunk 0..15
            const float4 v = *(const float4*)(qdb + (j0 + qrow)*EDIM + e0 + c*4);
            *(float4*)(sqd + qrow*64 + ((c ^ (qrow & 15)) << 2)) = v;
        }
    }
    __syncthreads();

    const u16* sq = (const u16*)sq4;
    const u16* sp = (const u16*)sp4;
    const int csw = col & 7;   // row&7 for row = *t*16+col

    #pragma unroll 1
    for (int t = 0; t < 2; ++t) {
        const int i = i0 + wid + t*4;      // each wave: 2 of the block's 8 i's

        float kdv[4];
        #pragma unroll
        for (int et = 0; et < 4; ++et)
            kdv[et] = kdg[i*EDIM + e0 + et*16 + col];

        floatx4 acc[4][4];
        #pragma unroll
        for (int mt = 0; mt < 4; ++mt)
            #pragma unroll
            for (int et = 0; et < 4; ++et) {
                const float nk = -kdv[et];
                acc[mt][et] = floatx4{nk, nk, nk, nk};
            }

        const u16* kp = kg + i*DIM + quad*8;
        #pragma unroll
        for (int ks = 0; ks < 8; ++ks) {
            const f16x8 kv = __builtin_bit_cast(f16x8, *(const uint4*)(kp + ks*32));
            const int cs = ((ks*4 + quad) ^ csw) * 8;
            f16x8 bf[4], sa[4];
            #pragma unroll
            for (int et = 0; et < 4; ++et)
                bf[et] = *(const f16x8*)(sp + (et*16 + col)*DIM + cs);
            #pragma unroll
            for (int mt = 0; mt < 4; ++mt) {
                const f16x8 af = *(const f16x8*)(sq + (mt*16 + col)*DIM + cs);
                sa[mt] = af * kv;          // v_pk_mul_f16 x4
            }
            #pragma unroll
            for (int mt = 0; mt < 4; ++mt)
                #pragma unroll
                for (int et = 0; et < 4; ++et)
                    acc[mt][et] = __builtin_amdgcn_mfma_f32_16x16x32_f16(
                        sa[mt], bf[et], acc[mt][et], 0, 0, 0);
        }

        // epilogue: out = acc + qd (from LDS) ; kd already folded into init
        float* ob = outp + (size_t)i * (NTOK * EDIM);
        #pragma unroll
        for (int mt = 0; mt < 4; ++mt) {
            #pragma unroll
            for (int et = 0; et < 4; ++et) {
                const int e_loc  = et*16 + col;         // 0..63
                const int chunk  = e_loc >> 2;
                const int within = e_loc & 3;
                const int ec     = e0 + e_loc;
                #pragma unroll
                for (int r = 0; r < 4; ++r) {
                    const int row = mt*16 + quad*4 + r; // 0..63
                    const float qd = sqd[row*64 + ((chunk ^ (row & 15)) << 2) + within];
                    ob[(j0 + row) * EDIM + ec] = acc[mt][et][r] + qd;
                }
            }
        }
    }
}

extern "C" void kernel_launch(void* const* d_in, const int* in_sizes, int n_in,
                              void* d_out, int out_size, void* d_ws, size_t ws_size,
                              hipStream_t stream) {
    const float* node   = (const float*)d_in[0];
    const float* ln_w   = (const float*)d_in[1];
    const float* ln_b   = (const float*)d_in[2];
    const float* proj_w = (const float*)d_in[3];
    const float* proj_b = (const float*)d_in[4];
    const float* o_w    = (const float*)d_in[5];
    const float* o_b    = (const float*)d_in[6];
    float* outp = (float*)d_out;

    // ws: q f16[512][256] | k f16[512][256] | wp f16[128][256] | qdb f32[512][128] | kd f32[512][128]
    u16*   qws = (u16*)d_ws;
    u16*   kws = qws + NTOK*DIM;
    u16*   wpf = kws + NTOK*DIM;
    float* qdb = (float*)(wpf + EDIM*DIM);
    float* kdw = qdb + NTOK*EDIM;

    hipLaunchKernelGGL(k1_ln_proj, dim3(144), dim3(256), 0, stream,
                       node, ln_w, ln_b, proj_w, proj_b, o_w, o_b,
                       qws, kws, wpf, qdb, kdw);
    hipLaunchKernelGGL(k2_edge, dim3(1024), dim3(256), 0, stream,
                       qws, kws, qdb, kdw, wpf, outp);
}

// Round 5
// 216.517 us; speedup vs baseline: 2.4812x; 1.4580x over previous
//
#include <hip/hip_runtime.h>

using u16 = unsigned short;
using u32 = unsigned int;

typedef __attribute__((ext_vector_type(8))) _Float16 f16x8;
typedef __attribute__((ext_vector_type(4))) float floatx4;

#define NTOK 512
#define DIM  256   // NODE_DIM == HIDDEN
#define EDIM 128

// ---------------------------------------------------------------------------
// Kernel 1: blocks 0..127: LayerNorm + proj (q,k) + qd/kd pre-GEMMs (4 rows
// per block).  Blocks 128..143: convert w_p = o_w[:,0:256] to f16.
// Outputs: q,k f16 [512][256]; wp f16 [128][256];
//          qdb = q@w_d^T + o_b (f32), kd = k@w_d^T (f32)
// ---------------------------------------------------------------------------
__global__ __launch_bounds__(256) void k1_ln_proj(
    const float* __restrict__ node, const float* __restrict__ ln_w,
    const float* __restrict__ ln_b, const float* __restrict__ proj_w,
    const float* __restrict__ proj_b, const float* __restrict__ o_w,
    const float* __restrict__ o_b,
    u16* __restrict__ qo, u16* __restrict__ ko, u16* __restrict__ wpf,
    float* __restrict__ qdb, float* __restrict__ kdo)
{
    const int tid = threadIdx.x;

    if (blockIdx.x >= 128) {
        // w_p f32 -> f16 conversion: 16 blocks x 256 thr x 8 elems = 128*256
        const int g   = (blockIdx.x - 128) * 256 + tid;
        const int idx = g * 8;
        const int e   = idx >> 8;
        const int h   = idx & 255;
        const float4 lo = *(const float4*)(o_w + e*(2*DIM) + h);
        const float4 hi = *(const float4*)(o_w + e*(2*DIM) + h + 4);
        f16x8 v;
        v[0] = (_Float16)lo.x; v[1] = (_Float16)lo.y;
        v[2] = (_Float16)lo.z; v[3] = (_Float16)lo.w;
        v[4] = (_Float16)hi.x; v[5] = (_Float16)hi.y;
        v[6] = (_Float16)hi.z; v[7] = (_Float16)hi.w;
        *(f16x8*)(wpf + idx) = v;
        return;
    }

    __shared__ float sn[4][DIM];       // normalized rows
    __shared__ float sfull[4][2*DIM];  // s = LN@proj_w^T + proj_b (q|k concat)
    const int wid  = tid >> 6;
    const int lane = tid & 63;
    const int n0   = blockIdx.x * 4;

    // --- LayerNorm: wave w -> row n0+w ---
    {
        const int n = n0 + wid;
        const int d = lane * 4;
        const float4 x = *(const float4*)(node + n*DIM + d);
        float s  = x.x + x.y + x.z + x.w;
        float ss = x.x*x.x + x.y*x.y + x.z*x.z + x.w*x.w;
        #pragma unroll
        for (int off = 32; off > 0; off >>= 1) {
            s  += __shfl_xor(s,  off);
            ss += __shfl_xor(ss, off);
        }
        const float mu   = s * (1.0f/DIM);
        const float var  = ss * (1.0f/DIM) - mu*mu;
        const float rstd = rsqrtf(var + 1e-5f);
        const float4 w = *(const float4*)(ln_w + d);
        const float4 b = *(const float4*)(ln_b + d);
        sn[wid][d+0] = (x.x-mu)*rstd*w.x + b.x;
        sn[wid][d+1] = (x.y-mu)*rstd*w.y + b.y;
        sn[wid][d+2] = (x.z-mu)*rstd*w.z + b.z;
        sn[wid][d+3] = (x.w-mu)*rstd*w.w + b.w;
    }
    __syncthreads();

    // --- proj: thread t computes cols c0=t (q) and c1=t+256 (k), 4 rows ---
    {
        const int c0 = tid, c1 = tid + DIM;
        const float bq = proj_b[c0], bk = proj_b[c1];
        float accq[4], acck[4];
        #pragma unroll
        for (int r = 0; r < 4; ++r) { accq[r] = bq; acck[r] = bk; }
        const float* w0p = proj_w + c0*DIM;
        const float* w1p = proj_w + c1*DIM;
        for (int d = 0; d < DIM; d += 4) {
            const float4 wa = *(const float4*)(w0p + d);
            const float4 wb = *(const float4*)(w1p + d);
            #pragma unroll
            for (int r = 0; r < 4; ++r) {
                const float s0 = sn[r][d+0], s1 = sn[r][d+1];
                const float s2 = sn[r][d+2], s3 = sn[r][d+3];
                accq[r] += wa.x*s0 + wa.y*s1 + wa.z*s2 + wa.w*s3;
                acck[r] += wb.x*s0 + wb.y*s1 + wb.z*s2 + wb.w*s3;
            }
        }
        #pragma unroll
        for (int r = 0; r < 4; ++r) {
            sfull[r][c0] = accq[r];
            sfull[r][c1] = acck[r];
            qo[(n0+r)*DIM + c0] = __builtin_bit_cast(u16, (_Float16)accq[r]);
            ko[(n0+r)*DIM + c0] = __builtin_bit_cast(u16, (_Float16)acck[r]);
        }
    }
    __syncthreads();

    // --- qd[n,e] = q[n,:]·w_d[e,:] + o_b[e] ;  kd[n,e] = k[n,:]·w_d[e,:] ---
    {
        const int e    = tid & (EDIM-1);
        const int half = tid >> 7;             // 0: qd (q part), 1: kd (k part)
        const float* wd = o_w + e*(2*DIM) + DIM;  // w_d = o_w[:, 256:512]
        float a[4] = {0.f, 0.f, 0.f, 0.f};
        for (int h = 0; h < DIM; h += 4) {
            const float4 w = *(const float4*)(wd + h);
            #pragma unroll
            for (int r = 0; r < 4; ++r) {
                const float* sp = &sfull[r][half*DIM + h];
                a[r] += w.x*sp[0] + w.y*sp[1] + w.z*sp[2] + w.w*sp[3];
            }
        }
        if (half == 0) {
            const float ob = o_b[e];
            #pragma unroll
            for (int r = 0; r < 4; ++r) qdb[(n0+r)*EDIM + e] = a[r] + ob;
        } else {
            #pragma unroll
            for (int r = 0; r < 4; ++r) kdo[(n0+r)*EDIM + e] = a[r];
        }
    }
}

// ---------------------------------------------------------------------------
// Kernel 2: x[i,j,e] = (q[j,:]*k[i,:])·w_p[e,:] + qd[j,e] - kd[i,e]
// Grid: 1024 blocks = 2 e-tiles(64) x 8 j-tiles(64) x 64 i-groups(8).
// Block: 256 thr = 4 waves sharing one 64j x 64e tile; waves take 2 i's each.
// LDS (80 KB): q tile 32K + wp tile 32K (XOR-swizzled b128) + qd tile 16K.
// NO __launch_bounds__ min-occupancy clamp: rounds 3/4 showed it resolves to
// a 128-VGPR cap while demand is ~190 -> ~200 dwords/thread scratch spill
// (205 MB symmetric FETCH/WRITE excess).  LDS already caps at 2 blocks/CU;
// let the allocator take ~190-220 VGPRs (2 waves/SIMD) with zero spill.
// Output stores are non-temporal (write-only 128 MB; keep L2 for tiles).
// ---------------------------------------------------------------------------
__global__ __launch_bounds__(256) void k2_edge(
    const u16* __restrict__ qg, const u16* __restrict__ kg,
    const float* __restrict__ qdb, const float* __restrict__ kdg,
    const u16* __restrict__ wpg, float* __restrict__ outp)
{
    __shared__ uint4 sq4[2048];   // q  tile: 64 rows x 32 swizzled 16B chunks
    __shared__ uint4 sp4[2048];   // wp tile: same layout
    __shared__ float sqd[4096];   // qd tile: 64j x 16 swizzled float4 chunks

    const int tid  = threadIdx.x;
    const int wid  = tid >> 6;
    const int lane = tid & 63;
    const int col  = lane & 15;
    const int quad = lane >> 4;
    const int bid  = blockIdx.x;
    const int e0 = (bid & 1) * 64;
    const int j0 = ((bid >> 1) & 7) * 64;
    const int i0 = (bid >> 4) * 8;

    // --- stage q[j0:+64][0:256], wp[e0:+64][0:256] (f16), qd[j0:+64][e0:+64] ---
    {
        const int row   = tid >> 2;        // 0..63
        const int cbase = (tid & 3) * 8;   // chunk base (chunk = 8 f16 = 16B)
        const int sw    = row & 7;
        #pragma unroll
        for (int u = 0; u < 8; ++u) {
            const int c = cbase + u;
            sq4[row*32 + (c ^ sw)] = *(const uint4*)(qg  + (j0 + row)*DIM + c*8);
            sp4[row*32 + (c ^ sw)] = *(const uint4*)(wpg + (e0 + row)*DIM + c*8);
        }
        // qd: lane=row, wave w stages float4-chunks 4w..4w+3, chunk-XOR swizzle
        const int qrow = tid & 63;
        const int cb   = (tid >> 6) * 4;
        #pragma unroll
        for (int u = 0; u < 4; ++u) {
            const int c = cb + u;          // float4 chunk 0..15
            const float4 v = *(const float4*)(qdb + (j0 + qrow)*EDIM + e0 + c*4);
            *(float4*)(sqd + qrow*64 + ((c ^ (qrow & 15)) << 2)) = v;
        }
    }
    __syncthreads();

    const u16* sq = (const u16*)sq4;
    const u16* sp = (const u16*)sp4;
    const int csw = col & 7;   // row&7 for row = *t*16+col

    #pragma unroll 1
    for (int t = 0; t < 2; ++t) {
        const int i = i0 + wid + t*4;      // each wave: 2 of the block's 8 i's

        // hoist the whole k[i,:] row into registers (32 VGPRs, deliberate)
        f16x8 kv[8];
        const u16* kp = kg + i*DIM + quad*8;
        #pragma unroll
        for (int ks = 0; ks < 8; ++ks)
            kv[ks] = __builtin_bit_cast(f16x8, *(const uint4*)(kp + ks*32));

        float kdv[4];
        #pragma unroll
        for (int et = 0; et < 4; ++et)
            kdv[et] = kdg[i*EDIM + e0 + et*16 + col];

        floatx4 acc[4][4];
        #pragma unroll
        for (int mt = 0; mt < 4; ++mt)
            #pragma unroll
            for (int et = 0; et < 4; ++et) {
                const float nk = -kdv[et];
                acc[mt][et] = floatx4{nk, nk, nk, nk};
            }

        #pragma unroll
        for (int ks = 0; ks < 8; ++ks) {
            const int cs = ((ks*4 + quad) ^ csw) * 8;
            f16x8 bf[4];
            #pragma unroll
            for (int et = 0; et < 4; ++et)
                bf[et] = *(const f16x8*)(sp + (et*16 + col)*DIM + cs);
            #pragma unroll
            for (int mt = 0; mt < 4; ++mt) {
                const f16x8 af = *(const f16x8*)(sq + (mt*16 + col)*DIM + cs);
                const f16x8 sa = af * kv[ks];   // v_pk_mul_f16 x4
                #pragma unroll
                for (int et = 0; et < 4; ++et)
                    acc[mt][et] = __builtin_amdgcn_mfma_f32_16x16x32_f16(
                        sa, bf[et], acc[mt][et], 0, 0, 0);
            }
        }

        // epilogue: out = acc + qd (from LDS) ; kd already folded into init
        float* ob = outp + (size_t)i * (NTOK * EDIM);
        #pragma unroll
        for (int mt = 0; mt < 4; ++mt) {
            #pragma unroll
            for (int et = 0; et < 4; ++et) {
                const int e_loc  = et*16 + col;         // 0..63
                const int chunk  = e_loc >> 2;
                const int within = e_loc & 3;
                const int ec     = e0 + e_loc;
                #pragma unroll
                for (int r = 0; r < 4; ++r) {
                    const int row = mt*16 + quad*4 + r; // 0..63
                    const float qd = sqd[row*64 + ((chunk ^ (row & 15)) << 2) + within];
                    __builtin_nontemporal_store(acc[mt][et][r] + qd,
                                                ob + (j0 + row) * EDIM + ec);
                }
            }
        }
    }
}

extern "C" void kernel_launch(void* const* d_in, const int* in_sizes, int n_in,
                              void* d_out, int out_size, void* d_ws, size_t ws_size,
                              hipStream_t stream) {
    const float* node   = (const float*)d_in[0];
    const float* ln_w   = (const float*)d_in[1];
    const float* ln_b   = (const float*)d_in[2];
    const float* proj_w = (const float*)d_in[3];
    const float* proj_b = (const float*)d_in[4];
    const float* o_w    = (const float*)d_in[5];
    const float* o_b    = (const float*)d_in[6];
    float* outp = (float*)d_out;

    // ws: q f16[512][256] | k f16[512][256] | wp f16[128][256] | qdb f32[512][128] | kd f32[512][128]
    u16*   qws = (u16*)d_ws;
    u16*   kws = qws + NTOK*DIM;
    u16*   wpf = kws + NTOK*DIM;
    float* qdb = (float*)(wpf + EDIM*DIM);
    float* kdw = qdb + NTOK*EDIM;

    hipLaunchKernelGGL(k1_ln_proj, dim3(144), dim3(256), 0, stream,
                       node, ln_w, ln_b, proj_w, proj_b, o_w, o_b,
                       qws, kws, wpf, qdb, kdw);
    hipLaunchKernelGGL(k2_edge, dim3(1024), dim3(256), 0, stream,
                       qws, kws, qdb, kdw, wpf, outp);
}